// Round 8
// baseline (1485.447 us; speedup 1.0000x reference)
//
#include <hip/hip_runtime.h>
#include <hip/hip_bf16.h>
#include <math.h>

typedef __bf16 bf16x8 __attribute__((ext_vector_type(8)));
typedef float  f32x4  __attribute__((ext_vector_type(4)));

#define SRC 4096
#define BSZ 64
#define EMB 512
#define SBLK 8   // s-slices per fused block; grid = 512

// ---- fused prep: blk0 = normed_v; blk 1..128 = pack Wv; blk 129..256 = pqb ----
__global__ void prep_all(const float* __restrict__ query, const float* __restrict__ Wq,
                         const float* __restrict__ bias, const float* __restrict__ v,
                         const float* __restrict__ g, const float* __restrict__ Wv,
                         float* __restrict__ nv, float* __restrict__ pqb,
                         __bf16* __restrict__ wvpk) {
  __shared__ float sh[EMB];
  __shared__ float red[256];
  const int blk = blockIdx.x, t = threadIdx.x;
  if (blk == 0) {
    float a = v[t], b = v[t + 256];
    red[t] = a * a + b * b;
    __syncthreads();
    for (int o = 128; o > 0; o >>= 1) {
      if (t < o) red[t] += red[t + o];
      __syncthreads();
    }
    float scale = g[0] / sqrtf(red[0]);
    nv[t]       = a * scale;
    nv[t + 256] = b * scale;
  } else if (blk <= 128) {
    int tid  = (blk - 1) * 256 + t;   // 0..32767
    int lane = tid & 63;
    int ks   = (tid >> 6) & 15;
    int nsub = tid >> 10;
    int e  = nsub * 16 + (lane & 15);
    int k0 = ks * 32 + (lane >> 4) * 8;
    const float* src = Wv + (size_t)e * EMB + k0;
    bf16x8 o;
#pragma unroll
    for (int j = 0; j < 8; ++j) o[j] = (__bf16)src[j];
    *reinterpret_cast<bf16x8*>(wvpk + (size_t)tid * 8) = o;
  } else {
    int bb = blk - 129;               // 0..127
    int b = bb >> 1;
    int e = (bb & 1) * 256 + t;
    sh[t]       = query[b * EMB + t];
    sh[t + 256] = query[b * EMB + t + 256];
    __syncthreads();
    const float* wr = Wq + (size_t)e * EMB;
    float a0 = 0.f, a1 = 0.f;
#pragma unroll 8
    for (int k = 0; k < EMB; k += 8) {
      float4 q0 = *reinterpret_cast<const float4*>(&sh[k]);
      float4 w0 = *reinterpret_cast<const float4*>(&wr[k]);
      float4 q1 = *reinterpret_cast<const float4*>(&sh[k + 4]);
      float4 w1 = *reinterpret_cast<const float4*>(&wr[k + 4]);
      a0 += q0.x * w0.x + q0.y * w0.y + q0.z * w0.z + q0.w * w0.w;
      a1 += q1.x * w1.x + q1.y * w1.y + q1.z * w1.z + q1.w * w1.w;
    }
    pqb[b * EMB + e] = a0 + a1 + bias[e];
  }
}

// ---- fused scores + unnormalized context partials.
// Per block: SBLK s-slices. Per slice: stage value[s] (f32->bf16, swizzled LDS),
// MFMA scores, tanh/nv epilogue, reduce -> score[s][b]; then e = mask?0:exp(score)
// (valid without max subtraction: |score| <= sqrt(512)*g = 1.0 analytically) and
// U[b][v] += e[b]*value[s][b][v] with value re-read f32 from L2 (just staged).
// parts[blk] = U at block end; ctx_reduce sums and divides by Z.
// Register budget: acc 64 + bq 32 + U 64 + sc 16 + addr ~25 = ~200 < 256
// (launch_bounds(512,1) -> 2 waves/SIMD, 256-VGPR cap). Do NOT raise occupancy:
// at (512,2) the 128-reg cap spills U (v2 lesson: 3.9 GB scratch, 10x slower).
__global__ __launch_bounds__(512, 1)
void scores_ctx(const float* __restrict__ value, const float* __restrict__ pqb,
                const float* __restrict__ nv, const __bf16* __restrict__ wvpk,
                const unsigned char* __restrict__ mask,
                float* __restrict__ scoresT, float* __restrict__ parts) {
  __shared__ __bf16 As[BSZ * EMB];   // 64 KB; elem(row,kg*8+i) at row*512 + ((kg^(row&7))*8+i)
  __shared__ float red[8][BSZ];
  __shared__ float esh[BSZ];
  const int sb = blockIdx.x * SBLK;
  const int t  = threadIdx.x;
  const int row = t >> 3, sub = t & 7, swz = row & 7;
  const int w = t >> 6, l = t & 63, lr = l & 15, lk = l >> 4;
  const __bf16* bp = wvpk + (size_t)(w * 4) * 16 * 512 + (size_t)l * 8;

  // ctx partial accumulators: thread t, step j owns element
  // (b = j*4 + (t>>7), v = (t&127)*4 .. +4)  -> lane-contiguous 16B loads/stores
  float4 U[16];
#pragma unroll
  for (int j = 0; j < 16; ++j) U[j] = make_float4(0.f, 0.f, 0.f, 0.f);

  for (int is = 0; is < SBLK; ++is) {
    const int s = sb + is;

    // ---- stage value[s] as bf16 into swizzled LDS ----
    {
      const float* src = value + (size_t)s * (BSZ * EMB) + (size_t)row * EMB + sub * 8;
#pragma unroll
      for (int j = 0; j < 8; ++j) {
        float4 v0 = *reinterpret_cast<const float4*>(src + j * 64);
        float4 v1 = *reinterpret_cast<const float4*>(src + j * 64 + 4);
        int kgp = (sub + j * 8) ^ swz;
        bf16x8 o;
        o[0] = (__bf16)v0.x; o[1] = (__bf16)v0.y; o[2] = (__bf16)v0.z; o[3] = (__bf16)v0.w;
        o[4] = (__bf16)v1.x; o[5] = (__bf16)v1.y; o[6] = (__bf16)v1.z; o[7] = (__bf16)v1.w;
        *reinterpret_cast<bf16x8*>(&As[row * EMB + kgp * 8]) = o;
      }
    }
    __syncthreads();   // A: stage complete (prev slice's esh/ctx reads also done)

    // ---- MFMA scores ----
    f32x4 acc[4][4];
#pragma unroll
    for (int m = 0; m < 4; ++m)
#pragma unroll
      for (int n = 0; n < 4; ++n)
#pragma unroll
        for (int r = 0; r < 4; ++r) acc[m][n][r] = 0.f;

    bf16x8 bq[2][4];
#pragma unroll
    for (int n = 0; n < 4; ++n)
      bq[0][n] = *reinterpret_cast<const bf16x8*>(bp + (size_t)(n * 16) * 512);

#pragma unroll
    for (int ksg = 0; ksg < 16; ++ksg) {
      if (ksg < 15) {
#pragma unroll
        for (int n = 0; n < 4; ++n)
          bq[(ksg + 1) & 1][n] =
              *reinterpret_cast<const bf16x8*>(bp + (size_t)(n * 16 + ksg + 1) * 512);
      }
      const int kgp = ((ksg * 4 + lk) ^ (lr & 7)) * 8;
#pragma unroll
      for (int m = 0; m < 4; ++m) {
        bf16x8 a = *reinterpret_cast<const bf16x8*>(&As[(m * 16 + lr) * EMB + kgp]);
#pragma unroll
        for (int n = 0; n < 4; ++n)
          acc[m][n] = __builtin_amdgcn_mfma_f32_16x16x32_bf16(a, bq[ksg & 1][n], acc[m][n], 0, 0, 0);
      }
    }

    // ---- fused epilogue: sc[b-part] += nv[col]*tanh(acc + pqb) ----
    float sc[16];
#pragma unroll
    for (int i = 0; i < 16; ++i) sc[i] = 0.f;
#pragma unroll
    for (int n = 0; n < 4; ++n) {
      int col = w * 64 + n * 16 + lr;
      float nvc = nv[col];
#pragma unroll
      for (int m = 0; m < 4; ++m) {
#pragma unroll
        for (int r = 0; r < 4; ++r) {
          int brow = m * 16 + lk * 4 + r;
          float x = acc[m][n][r] + pqb[brow * EMB + col];
          // tanh(x) = 1 - 2/(1+exp(2x)) — monotone-safe at both infinities
          float e = __expf(2.0f * x);
          float rcp = __builtin_amdgcn_rcpf(1.0f + e);
          sc[m * 4 + r] += fmaf(-2.0f * nvc, rcp, nvc);
        }
      }
    }

#pragma unroll
    for (int i = 0; i < 16; ++i) {
      float vsum = sc[i];
#pragma unroll
      for (int off = 1; off < 16; off <<= 1) vsum += __shfl_xor(vsum, off, 64);
      if (lr == 0) red[w][(i >> 2) * 16 + lk * 4 + (i & 3)] = vsum;
    }
    __syncthreads();   // B: red complete, As reads done

    if (t < BSZ) {
      float total = 0.f;
#pragma unroll
      for (int ww = 0; ww < 8; ++ww) total += red[ww][t];
      scoresT[(size_t)t * SRC + s] = total;
      esh[t] = mask[(size_t)s * BSZ + t] ? 0.f : __expf(total);
    }
    __syncthreads();   // C: esh ready

    // ---- ctx accumulate: U += e[b] * value[s] (f32 re-read, L2-hot) ----
    {
      const float* vs = value + (size_t)s * (BSZ * EMB);
#pragma unroll
      for (int j = 0; j < 16; ++j) {
        float eb = esh[j * 4 + (t >> 7)];
        float4 vv = *reinterpret_cast<const float4*>(vs + (size_t)(j * 512 + t) * 4);
        U[j].x = fmaf(eb, vv.x, U[j].x);
        U[j].y = fmaf(eb, vv.y, U[j].y);
        U[j].z = fmaf(eb, vv.z, U[j].z);
        U[j].w = fmaf(eb, vv.w, U[j].w);
      }
    }
    // next stage's As overwrite is safe: it comes after barrier A of the next
    // iteration; esh overwrite comes after the next B barrier.
  }

  // ---- write unnormalized partials ----
  float* dst = parts + (size_t)blockIdx.x * (BSZ * EMB);
#pragma unroll
  for (int j = 0; j < 16; ++j)
    *reinterpret_cast<float4*>(dst + (size_t)(j * 512 + t) * 4) = U[j];
}

// ---- softmax over s for each b (no-max variant; also emits Z for ctx_reduce) ----
// |score| <= ||nv||_1 <= sqrt(512)*||nv||_2 = sqrt(512)*g = 1.0 (data-independent),
// so exp in [0.37, 2.72]; max-subtraction unnecessary.
__global__ void softmax_k(const float* __restrict__ scoresT, const unsigned char* __restrict__ mask,
                          float* __restrict__ Z, float* __restrict__ attn0,
                          float* __restrict__ attn1) {
  __shared__ float buf[SRC];
  __shared__ float red[256];
  int b = blockIdx.x, t = threadIdx.x;
  float sum = 0.f;
  for (int s = t; s < SRC; s += 256) {
    float x = scoresT[(size_t)b * SRC + s];
    float e = mask[(size_t)s * BSZ + b] ? 0.f : __expf(x);
    buf[s] = e;
    sum += e;
  }
  red[t] = sum; __syncthreads();
  for (int o = 128; o > 0; o >>= 1) { if (t < o) red[t] += red[t + o]; __syncthreads(); }
  if (t == 0) Z[b] = red[0];
  float inv = 1.0f / red[0];
  for (int s = t; s < SRC; s += 256) {
    float p = buf[s] * inv;
    attn0[(size_t)s * BSZ + b] = p;
    attn1[(size_t)s * BSZ + b] = p;
  }
}

// ---- ctx_reduce: out[b][v] = (sum over 512 blocks of parts)[b][v] / Z[b] ----
// 256 blocks x 256 thr; block owns 32 float4-cols; 8 j-groups of 64 slabs each.
__global__ __launch_bounds__(256)
void ctx_reduce(const float* __restrict__ parts, const float* __restrict__ Z,
                float* __restrict__ out_ctx) {
  __shared__ float4 red4[32][8];
  const int t = threadIdx.x;
  const int c = t & 31, jg = t >> 5;
  const int col = blockIdx.x * 32 + c;        // float4 column 0..8191
  const float* src = parts + (size_t)(jg * 64) * (BSZ * EMB) + (size_t)col * 4;
  float4 acc = make_float4(0.f, 0.f, 0.f, 0.f);
#pragma unroll 8
  for (int j = 0; j < 64; ++j) {
    float4 vv = *reinterpret_cast<const float4*>(src + (size_t)j * (BSZ * EMB));
    acc.x += vv.x; acc.y += vv.y; acc.z += vv.z; acc.w += vv.w;
  }
  red4[c][jg] = acc;
  __syncthreads();
  if (t < 32) {
    const int cc = t;
    float4 s0 = red4[cc][0];
#pragma unroll
    for (int k = 1; k < 8; ++k) {
      float4 v = red4[cc][k];
      s0.x += v.x; s0.y += v.y; s0.z += v.z; s0.w += v.w;
    }
    const int colw = blockIdx.x * 32 + cc;
    const float invz = 1.0f / Z[colw >> 7];   // b = (colw*4)/512
    s0.x *= invz; s0.y *= invz; s0.z *= invz; s0.w *= invz;
    *reinterpret_cast<float4*>(out_ctx + (size_t)colw * 4) = s0;
  }
}

extern "C" void kernel_launch(void* const* d_in, const int* in_sizes, int n_in,
                              void* d_out, int out_size, void* d_ws, size_t ws_size,
                              hipStream_t stream) {
  const float* query        = (const float*)d_in[0];
  const float* value        = (const float*)d_in[1];
  const unsigned char* mask = (const unsigned char*)d_in[2];
  const float* Wq           = (const float*)d_in[3];
  const float* Wv           = (const float*)d_in[4];
  const float* v            = (const float*)d_in[5];
  const float* bias         = (const float*)d_in[6];
  const float* g            = (const float*)d_in[7];

  float* out_ctx = (float*)d_out;              // [64][512]
  float* attn0   = (float*)d_out + BSZ * EMB;  // [4096][64]
  float* attn1   = attn0 + SRC * BSZ;

  char* ws = (char*)d_ws;
  float*  nv      = (float*)(ws);                      // 2 KB
  float*  pqb     = (float*)(ws + 2048);               // 128 KB
  __bf16* wvpk    = (__bf16*)(ws + 133120);            // 512 KB
  float*  scoresT = (float*)(ws + 657408);             // 1 MB [b][s]
  float*  Zbuf    = (float*)(ws + 1705984);            // 4 KB (64 floats + pad)
  float*  parts   = (float*)(ws + 1710080);            // 64 MB [512][64][512]

  prep_all<<<257, 256, 0, stream>>>(query, Wq, bias, v, g, Wv, nv, pqb, wvpk);
  scores_ctx<<<SRC / SBLK, 512, 0, stream>>>(value, pqb, nv, wvpk, mask, scoresT, parts);
  softmax_k<<<BSZ, 256, 0, stream>>>(scoresT, mask, Zbuf, attn0, attn1);
  ctx_reduce<<<256, 256, 0, stream>>>(parts, Zbuf, out_ctx);
}

// Round 12
// 1436.582 us; speedup vs baseline: 1.0340x; 1.0340x over previous
//
#include <hip/hip_runtime.h>
#include <hip/hip_bf16.h>
#include <math.h>

typedef __bf16 bf16x8 __attribute__((ext_vector_type(8)));
typedef __bf16 bf16x4 __attribute__((ext_vector_type(4)));
typedef float  f32x4  __attribute__((ext_vector_type(4)));

#define SRC 4096
#define BSZ 64
#define EMB 512
#define SBLK 8   // s-slices per fused block; grid = 512

// ---- fused prep: blk0 = normed_v; blk 1..128 = pack Wv; blk 129..256 = pqb ----
__global__ void prep_all(const float* __restrict__ query, const float* __restrict__ Wq,
                         const float* __restrict__ bias, const float* __restrict__ v,
                         const float* __restrict__ g, const float* __restrict__ Wv,
                         float* __restrict__ nv, float* __restrict__ pqb,
                         __bf16* __restrict__ wvpk) {
  __shared__ float sh[EMB];
  __shared__ float red[256];
  const int blk = blockIdx.x, t = threadIdx.x;
  if (blk == 0) {
    float a = v[t], b = v[t + 256];
    red[t] = a * a + b * b;
    __syncthreads();
    for (int o = 128; o > 0; o >>= 1) {
      if (t < o) red[t] += red[t + o];
      __syncthreads();
    }
    float scale = g[0] / sqrtf(red[0]);
    nv[t]       = a * scale;
    nv[t + 256] = b * scale;
  } else if (blk <= 128) {
    int tid  = (blk - 1) * 256 + t;   // 0..32767
    int lane = tid & 63;
    int ks   = (tid >> 6) & 15;
    int nsub = tid >> 10;
    int e  = nsub * 16 + (lane & 15);
    int k0 = ks * 32 + (lane >> 4) * 8;
    const float* src = Wv + (size_t)e * EMB + k0;
    bf16x8 o;
#pragma unroll
    for (int j = 0; j < 8; ++j) o[j] = (__bf16)src[j];
    *reinterpret_cast<bf16x8*>(wvpk + (size_t)tid * 8) = o;
  } else {
    int bb = blk - 129;               // 0..127
    int b = bb >> 1;
    int e = (bb & 1) * 256 + t;
    sh[t]       = query[b * EMB + t];
    sh[t + 256] = query[b * EMB + t + 256];
    __syncthreads();
    const float* wr = Wq + (size_t)e * EMB;
    float a0 = 0.f, a1 = 0.f;
#pragma unroll 8
    for (int k = 0; k < EMB; k += 8) {
      float4 q0 = *reinterpret_cast<const float4*>(&sh[k]);
      float4 w0 = *reinterpret_cast<const float4*>(&wr[k]);
      float4 q1 = *reinterpret_cast<const float4*>(&sh[k + 4]);
      float4 w1 = *reinterpret_cast<const float4*>(&wr[k + 4]);
      a0 += q0.x * w0.x + q0.y * w0.y + q0.z * w0.z + q0.w * w0.w;
      a1 += q1.x * w1.x + q1.y * w1.y + q1.z * w1.z + q1.w * w1.w;
    }
    pqb[b * EMB + e] = a0 + a1 + bias[e];
  }
}

// ---- fused scores + unnormalized context partials (v2).
// Per slice: stage value[s] f32->bf16 into swizzled LDS; MFMA scores; tanh/nv
// epilogue; e = mask?0:exp(score) (no-max legal: |score| <= sqrt(512)*g = 1.0);
// then ctx U[b][v] += e[b] * As[b][v] -- reading the bf16 tile ALREADY IN LDS,
// not global (round-8 lesson: the f32 re-read missed L2 because ~32 blocks/XCD
// stream 4 MB through L2 during the MFMA phase; +512 MB HBM).
// Register-cap control (round-8 lesson): the compiler caps VGPRs to match
// LDS-implied occupancy. As is padded +16 KB so LDS limits to 1 block/CU, and
// launch_bounds(512,2) sets the 256-reg cap; live arch state ~140 -> no spill.
__global__ __launch_bounds__(512, 2)
void scores_ctx(const float* __restrict__ value, const float* __restrict__ pqb,
                const float* __restrict__ nv, const __bf16* __restrict__ wvpk,
                const unsigned char* __restrict__ mask,
                float* __restrict__ scoresT, float* __restrict__ parts) {
  // 64 KB tile + 16 KB pad (pad forces 1 block/CU so the compiler targets
  // 2 waves/SIMD and allocates up to 256 VGPRs instead of 128+spill).
  __shared__ __bf16 As[BSZ * EMB + 8192];
  __shared__ float red[8][BSZ];
  __shared__ float esh[BSZ];
  const int sb = blockIdx.x * SBLK;
  const int t  = threadIdx.x;
  const int row = t >> 3, sub = t & 7, swz = row & 7;
  const int w = t >> 6, l = t & 63, lr = l & 15, lk = l >> 4;
  const __bf16* bp = wvpk + (size_t)(w * 4) * 16 * 512 + (size_t)l * 8;

  // ctx ownership: thread t, step j owns (b = j*4 + (t>>7), v = (t&127)*4..+4)
  const int v4 = t & 127, bh = t >> 7;
  const int kg = v4 >> 1;              // 16B granule within row (0..63)
  const int i2 = (v4 & 1) * 4;         // bf16 offset within granule (0 or 4)
  float4 U[16];
#pragma unroll
  for (int j = 0; j < 16; ++j) U[j] = make_float4(0.f, 0.f, 0.f, 0.f);

  for (int is = 0; is < SBLK; ++is) {
    const int s = sb + is;

    // ---- stage value[s] as bf16 into swizzled LDS ----
    {
      const float* src = value + (size_t)s * (BSZ * EMB) + (size_t)row * EMB + sub * 8;
#pragma unroll
      for (int j = 0; j < 8; ++j) {
        float4 v0 = *reinterpret_cast<const float4*>(src + j * 64);
        float4 v1 = *reinterpret_cast<const float4*>(src + j * 64 + 4);
        int kgp = (sub + j * 8) ^ swz;
        bf16x8 o;
        o[0] = (__bf16)v0.x; o[1] = (__bf16)v0.y; o[2] = (__bf16)v0.z; o[3] = (__bf16)v0.w;
        o[4] = (__bf16)v1.x; o[5] = (__bf16)v1.y; o[6] = (__bf16)v1.z; o[7] = (__bf16)v1.w;
        *reinterpret_cast<bf16x8*>(&As[row * EMB + kgp * 8]) = o;
      }
    }
    __syncthreads();   // A: stage complete

    // ---- MFMA scores ----
    f32x4 acc[4][4];
#pragma unroll
    for (int m = 0; m < 4; ++m)
#pragma unroll
      for (int n = 0; n < 4; ++n)
#pragma unroll
        for (int r = 0; r < 4; ++r) acc[m][n][r] = 0.f;

    bf16x8 bq[2][4];
#pragma unroll
    for (int n = 0; n < 4; ++n)
      bq[0][n] = *reinterpret_cast<const bf16x8*>(bp + (size_t)(n * 16) * 512);

#pragma unroll
    for (int ksg = 0; ksg < 16; ++ksg) {
      if (ksg < 15) {
#pragma unroll
        for (int n = 0; n < 4; ++n)
          bq[(ksg + 1) & 1][n] =
              *reinterpret_cast<const bf16x8*>(bp + (size_t)(n * 16 + ksg + 1) * 512);
      }
      const int kgp = ((ksg * 4 + lk) ^ (lr & 7)) * 8;
#pragma unroll
      for (int m = 0; m < 4; ++m) {
        bf16x8 a = *reinterpret_cast<const bf16x8*>(&As[(m * 16 + lr) * EMB + kgp]);
#pragma unroll
        for (int n = 0; n < 4; ++n)
          acc[m][n] = __builtin_amdgcn_mfma_f32_16x16x32_bf16(a, bq[ksg & 1][n], acc[m][n], 0, 0, 0);
      }
    }

    // ---- fused epilogue: sc[b-part] += nv[col]*tanh(acc + pqb) ----
    float sc[16];
#pragma unroll
    for (int i = 0; i < 16; ++i) sc[i] = 0.f;
#pragma unroll
    for (int n = 0; n < 4; ++n) {
      int col = w * 64 + n * 16 + lr;
      float nvc = nv[col];
#pragma unroll
      for (int m = 0; m < 4; ++m) {
#pragma unroll
        for (int r = 0; r < 4; ++r) {
          int brow = m * 16 + lk * 4 + r;
          float x = acc[m][n][r] + pqb[brow * EMB + col];
          // tanh(x) = 1 - 2/(1+exp(2x)) — monotone-safe at both infinities
          float e = __expf(2.0f * x);
          float rcp = __builtin_amdgcn_rcpf(1.0f + e);
          sc[m * 4 + r] += fmaf(-2.0f * nvc, rcp, nvc);
        }
      }
    }

#pragma unroll
    for (int i = 0; i < 16; ++i) {
      float vsum = sc[i];
#pragma unroll
      for (int off = 1; off < 16; off <<= 1) vsum += __shfl_xor(vsum, off, 64);
      if (lr == 0) red[w][(i >> 2) * 16 + lk * 4 + (i & 3)] = vsum;
    }
    __syncthreads();   // B: red complete, As MFMA-reads done

    if (t < BSZ) {
      float total = 0.f;
#pragma unroll
      for (int ww = 0; ww < 8; ++ww) total += red[ww][t];
      scoresT[(size_t)t * SRC + s] = total;
      esh[t] = mask[(size_t)s * BSZ + t] ? 0.f : __expf(total);
    }
    __syncthreads();   // C: esh ready

    // ---- ctx accumulate from LDS: U += e[b] * bf16(As[b][v0..v0+3]) ----
    // 64 lanes of a wave span 512 contiguous (granule-permuted) bytes of one
    // row -> conflict-free ds_read_b64.
#pragma unroll
    for (int j = 0; j < 16; ++j) {
      const int b = j * 4 + bh;
      const float eb = esh[b];
      bf16x4 av = *reinterpret_cast<const bf16x4*>(
          &As[b * EMB + ((kg ^ (b & 7)) << 3) + i2]);
      U[j].x = fmaf(eb, (float)av[0], U[j].x);
      U[j].y = fmaf(eb, (float)av[1], U[j].y);
      U[j].z = fmaf(eb, (float)av[2], U[j].z);
      U[j].w = fmaf(eb, (float)av[3], U[j].w);
    }
    __syncthreads();   // D: ctx As-reads done before next stage overwrites
  }

  // ---- write unnormalized partials ----
  float* dst = parts + (size_t)blockIdx.x * (BSZ * EMB);
#pragma unroll
  for (int j = 0; j < 16; ++j)
    *reinterpret_cast<float4*>(dst + (size_t)(j * 512 + t) * 4) = U[j];
}

// ---- softmax over s for each b (no-max variant; also emits Z for ctx_reduce) ----
// |score| <= ||nv||_1 <= sqrt(512)*||nv||_2 = sqrt(512)*g = 1.0 (data-independent),
// so exp in [0.37, 2.72]; max-subtraction unnecessary.
__global__ void softmax_k(const float* __restrict__ scoresT, const unsigned char* __restrict__ mask,
                          float* __restrict__ Z, float* __restrict__ attn0,
                          float* __restrict__ attn1) {
  __shared__ float buf[SRC];
  __shared__ float red[256];
  int b = blockIdx.x, t = threadIdx.x;
  float sum = 0.f;
  for (int s = t; s < SRC; s += 256) {
    float x = scoresT[(size_t)b * SRC + s];
    float e = mask[(size_t)s * BSZ + b] ? 0.f : __expf(x);
    buf[s] = e;
    sum += e;
  }
  red[t] = sum; __syncthreads();
  for (int o = 128; o > 0; o >>= 1) { if (t < o) red[t] += red[t + o]; __syncthreads(); }
  if (t == 0) Z[b] = red[0];
  float inv = 1.0f / red[0];
  for (int s = t; s < SRC; s += 256) {
    float p = buf[s] * inv;
    attn0[(size_t)s * BSZ + b] = p;
    attn1[(size_t)s * BSZ + b] = p;
  }
}

// ---- ctx_reduce: out[b][v] = (sum over 512 blocks of parts)[b][v] / Z[b] ----
// 256 blocks x 256 thr; block owns 32 float4-cols; 8 j-groups of 64 slabs each.
__global__ __launch_bounds__(256)
void ctx_reduce(const float* __restrict__ parts, const float* __restrict__ Z,
                float* __restrict__ out_ctx) {
  __shared__ float4 red4[32][8];
  const int t = threadIdx.x;
  const int c = t & 31, jg = t >> 5;
  const int col = blockIdx.x * 32 + c;        // float4 column 0..8191
  const float* src = parts + (size_t)(jg * 64) * (BSZ * EMB) + (size_t)col * 4;
  float4 acc = make_float4(0.f, 0.f, 0.f, 0.f);
#pragma unroll 8
  for (int j = 0; j < 64; ++j) {
    float4 vv = *reinterpret_cast<const float4*>(src + (size_t)j * (BSZ * EMB));
    acc.x += vv.x; acc.y += vv.y; acc.z += vv.z; acc.w += vv.w;
  }
  red4[c][jg] = acc;
  __syncthreads();
  if (t < 32) {
    const int cc = t;
    float4 s0 = red4[cc][0];
#pragma unroll
    for (int k = 1; k < 8; ++k) {
      float4 v = red4[cc][k];
      s0.x += v.x; s0.y += v.y; s0.z += v.z; s0.w += v.w;
    }
    const int colw = blockIdx.x * 32 + cc;
    const float invz = 1.0f / Z[colw >> 7];   // b = (colw*4)/512
    s0.x *= invz; s0.y *= invz; s0.z *= invz; s0.w *= invz;
    *reinterpret_cast<float4*>(out_ctx + (size_t)colw * 4) = s0;
  }
}

extern "C" void kernel_launch(void* const* d_in, const int* in_sizes, int n_in,
                              void* d_out, int out_size, void* d_ws, size_t ws_size,
                              hipStream_t stream) {
  const float* query        = (const float*)d_in[0];
  const float* value        = (const float*)d_in[1];
  const unsigned char* mask = (const unsigned char*)d_in[2];
  const float* Wq           = (const float*)d_in[3];
  const float* Wv           = (const float*)d_in[4];
  const float* v            = (const float*)d_in[5];
  const float* bias         = (const float*)d_in[6];
  const float* g            = (const float*)d_in[7];

  float* out_ctx = (float*)d_out;              // [64][512]
  float* attn0   = (float*)d_out + BSZ * EMB;  // [4096][64]
  float* attn1   = attn0 + SRC * BSZ;

  char* ws = (char*)d_ws;
  float*  nv      = (float*)(ws);                      // 2 KB
  float*  pqb     = (float*)(ws + 2048);               // 128 KB
  __bf16* wvpk    = (__bf16*)(ws + 133120);            // 512 KB
  float*  scoresT = (float*)(ws + 657408);             // 1 MB [b][s]
  float*  Zbuf    = (float*)(ws + 1705984);            // 4 KB (64 floats + pad)
  float*  parts   = (float*)(ws + 1710080);            // 64 MB [512][64][512]

  prep_all<<<257, 256, 0, stream>>>(query, Wq, bias, v, g, Wv, nv, pqb, wvpk);
  scores_ctx<<<SRC / SBLK, 512, 0, stream>>>(value, pqb, nv, wvpk, mask, scoresT, parts);
  softmax_k<<<BSZ, 256, 0, stream>>>(scoresT, mask, Zbuf, attn0, attn1);
  ctx_reduce<<<256, 256, 0, stream>>>(parts, Zbuf, out_ctx);
}